// Round 1
// baseline (121.133 us; speedup 1.0000x reference)
//
#include <hip/hip_runtime.h>
#include <hip/hip_bf16.h>
#include <float.h>
#include <math.h>

typedef short short8 __attribute__((ext_vector_type(8)));
typedef float f32x4  __attribute__((ext_vector_type(4)));

#define KEPS   1e-5f
#define DENOMC 1e-5f

__device__ __forceinline__ short f2bf(float x) {
    return __builtin_bit_cast(short, __float2bfloat16(x));
}

// unsorted top-10, slot 0 always holds the min (admission gate)
__device__ __forceinline__ void top10_insert(float (&lst)[10], float s) {
    if (s > lst[0]) {
        lst[0] = s;
        #pragma unroll
        for (int i = 1; i < 10; ++i) {
            float lo = fminf(lst[0], lst[i]);
            float hi = fmaxf(lst[0], lst[i]);
            lst[0] = lo; lst[i] = hi;
        }
    }
}

// ---------------------------------------------------------------------------
// Kernel 1: stream memory once. Per 64-row tile: scores S = m2_j - 2*q_b.m_j
// via bf16 MFMA (b = all 64 queries), per-lane top-3 per b-tile, plus
// column-sums / sum-of-squares partials for the closed-form mean.
// ---------------------------------------------------------------------------
__global__ __launch_bounds__(256) void ep_main(
    const float* __restrict__ q, const float* __restrict__ mem,
    float* __restrict__ part_top,    // [nb][64][10]
    float* __restrict__ part_sums,   // [nb][33]  (colsum[32], sumsq)
    int nb, int ntiles)
{
    const int tid  = threadIdx.x;
    const int lane = tid & 63;
    const int wave = tid >> 6;
    const int g    = lane >> 4;   // k-chunk group (0..3), k = 8g..8g+7
    const int c    = lane & 15;   // row-within-subtile / col(b)-within-tile
    const int bid  = blockIdx.x;

    // B fragments (K x N = 32 x 16): lane holds q[16n + c][8g .. 8g+8)
    short8 bfrag[4];
    #pragma unroll
    for (int n = 0; n < 4; ++n) {
        const float* qp = q + (n * 16 + c) * 32 + g * 8;
        float4 w0 = *(const float4*)qp;
        float4 w1 = *(const float4*)(qp + 4);
        short8 f;
        f[0]=f2bf(w0.x); f[1]=f2bf(w0.y); f[2]=f2bf(w0.z); f[3]=f2bf(w0.w);
        f[4]=f2bf(w1.x); f[5]=f2bf(w1.y); f[6]=f2bf(w1.z); f[7]=f2bf(w1.w);
        bfrag[n] = f;
    }

    float t1[4], t2[4], t3[4];
    #pragma unroll
    for (int n = 0; n < 4; ++n) { t1[n] = -FLT_MAX; t2[n] = -FLT_MAX; t3[n] = -FLT_MAX; }
    float cs[8];
    #pragma unroll
    for (int r = 0; r < 8; ++r) cs[r] = 0.f;
    float sumsq = 0.f;

    const size_t lane_off = (size_t)(wave * 16 + c) * 32 + (size_t)(g * 8);

    for (int tile = bid; tile < ntiles; tile += nb) {
        const float* p = mem + (size_t)tile * (64 * 32) + lane_off;
        float4 v0 = *(const float4*)p;
        float4 v1 = *(const float4*)(p + 4);

        float ps;
        ps = v0.x * v0.x;
        ps = fmaf(v0.y, v0.y, ps);
        ps = fmaf(v0.z, v0.z, ps);
        ps = fmaf(v0.w, v0.w, ps);
        ps = fmaf(v1.x, v1.x, ps);
        ps = fmaf(v1.y, v1.y, ps);
        ps = fmaf(v1.z, v1.z, ps);
        ps = fmaf(v1.w, v1.w, ps);
        sumsq += ps;
        cs[0] += v0.x; cs[1] += v0.y; cs[2] += v0.z; cs[3] += v0.w;
        cs[4] += v1.x; cs[5] += v1.y; cs[6] += v1.z; cs[7] += v1.w;

        // full row norm of row c (sum over the 4 k-chunk groups)
        float m2 = ps + __shfl_xor(ps, 16, 64);
        m2 = m2 + __shfl_xor(m2, 32, 64);
        // gather m2 for this lane's C-layout rows 4g+0..3
        float m2c0 = __shfl(m2, 4 * g + 0, 64);
        float m2c1 = __shfl(m2, 4 * g + 1, 64);
        float m2c2 = __shfl(m2, 4 * g + 2, 64);
        float m2c3 = __shfl(m2, 4 * g + 3, 64);

        // A fragment (M x K = 16 x 32): lane holds memrow(c)[8g .. 8g+8)
        short8 af;
        af[0]=f2bf(v0.x); af[1]=f2bf(v0.y); af[2]=f2bf(v0.z); af[3]=f2bf(v0.w);
        af[4]=f2bf(v1.x); af[5]=f2bf(v1.y); af[6]=f2bf(v1.z); af[7]=f2bf(v1.w);

        #pragma unroll
        for (int n = 0; n < 4; ++n) {
            f32x4 acc = {0.f, 0.f, 0.f, 0.f};
            acc = __builtin_amdgcn_mfma_f32_16x16x32_bf16(af, bfrag[n], acc, 0, 0, 0);
            // score = m2_j - 2*dot  (ranking-equivalent to sq; q2_b added later)
            float s0 = fmaf(-2.f, acc[0], m2c0);
            float s1 = fmaf(-2.f, acc[1], m2c1);
            float s2 = fmaf(-2.f, acc[2], m2c2);
            float s3 = fmaf(-2.f, acc[3], m2c3);
            // unconditional sorted top-3 update (5 ops each)
            #define T3UPD(S) { \
                float h1 = fmaxf(t1[n], (S)); float lo  = fminf(t1[n], (S)); \
                float h2 = fmaxf(t2[n], lo);  float lo2 = fminf(t2[n], lo);  \
                float h3 = fmaxf(t3[n], lo2); \
                t1[n] = h1; t2[n] = h2; t3[n] = h3; }
            T3UPD(s0) T3UPD(s1) T3UPD(s2) T3UPD(s3)
            #undef T3UPD
        }
    }

    // ---- block-level merge ----
    __shared__ float ltop[64][16][3];   // 12 KB
    __shared__ float red[4][4][8];
    __shared__ float ssred[4];

    const int slot = g + 4 * wave;      // 16 slots
    #pragma unroll
    for (int n = 0; n < 4; ++n) {
        const int b = n * 16 + c;
        ltop[b][slot][0] = t1[n];
        ltop[b][slot][1] = t2[n];
        ltop[b][slot][2] = t3[n];
    }
    #pragma unroll
    for (int r = 0; r < 8; ++r) {
        float v = cs[r];
        v += __shfl_xor(v, 1, 64);
        v += __shfl_xor(v, 2, 64);
        v += __shfl_xor(v, 4, 64);
        v += __shfl_xor(v, 8, 64);
        cs[r] = v;
    }
    float ssv = sumsq;
    ssv += __shfl_xor(ssv, 1, 64);
    ssv += __shfl_xor(ssv, 2, 64);
    ssv += __shfl_xor(ssv, 4, 64);
    ssv += __shfl_xor(ssv, 8, 64);
    ssv += __shfl_xor(ssv, 16, 64);
    ssv += __shfl_xor(ssv, 32, 64);
    if (c == 0) {
        #pragma unroll
        for (int r = 0; r < 8; ++r) red[wave][g][r] = cs[r];
    }
    if (lane == 0) ssred[wave] = ssv;
    __syncthreads();

    if (tid < 32) {
        float a = red[0][tid >> 3][tid & 7] + red[1][tid >> 3][tid & 7]
                + red[2][tid >> 3][tid & 7] + red[3][tid >> 3][tid & 7];
        part_sums[(size_t)bid * 33 + tid] = a;
    } else if (tid == 32) {
        part_sums[(size_t)bid * 33 + 32] = ssred[0] + ssred[1] + ssred[2] + ssred[3];
    }

    if (tid < 64) {
        float lst[10];
        #pragma unroll
        for (int i = 0; i < 10; ++i) lst[i] = -FLT_MAX;
        for (int s2 = 0; s2 < 16; ++s2) {
            #pragma unroll
            for (int e = 0; e < 3; ++e) top10_insert(lst, ltop[tid][s2][e]);
        }
        #pragma unroll
        for (int i = 0; i < 10; ++i)
            part_top[((size_t)bid * 64 + tid) * 10 + i] = lst[i];
    }
}

// ---------------------------------------------------------------------------
// Kernel 2: reduce partial sums -> closed-form mean of sq over all B*M pairs.
// ---------------------------------------------------------------------------
__global__ __launch_bounds__(256) void ep_mean(
    const float* __restrict__ q, const float* __restrict__ part_sums,
    float* __restrict__ mean_out, int nb, int Mrows)
{
    const int tid = threadIdx.x;
    __shared__ float lds33[33][256];
    __shared__ float colsum_s[33];
    __shared__ float r4[4];

    float acc[33];
    #pragma unroll
    for (int c2 = 0; c2 < 33; ++c2) acc[c2] = 0.f;
    for (int i = tid; i < nb; i += 256) {
        const float* ps = part_sums + (size_t)i * 33;
        #pragma unroll
        for (int c2 = 0; c2 < 33; ++c2) acc[c2] += ps[c2];
    }
    #pragma unroll
    for (int c2 = 0; c2 < 33; ++c2) lds33[c2][tid] = acc[c2];
    __syncthreads();
    if (tid < 33) {
        float a = 0.f;
        #pragma unroll 16
        for (int j = 0; j < 256; ++j) a += lds33[tid][j];
        colsum_s[tid] = a;
    }

    // sum of squares of all query elements (= sum_b q2_b)
    float a2 = 0.f;
    #pragma unroll
    for (int e = 0; e < 8; ++e) {
        float x = q[tid * 8 + e];
        a2 = fmaf(x, x, a2);
    }
    a2 += __shfl_xor(a2, 1, 64);
    a2 += __shfl_xor(a2, 2, 64);
    a2 += __shfl_xor(a2, 4, 64);
    a2 += __shfl_xor(a2, 8, 64);
    a2 += __shfl_xor(a2, 16, 64);
    a2 += __shfl_xor(a2, 32, 64);
    if ((tid & 63) == 0) r4[tid >> 6] = a2;
    __syncthreads();

    float dq = 0.f;
    if (tid < 32) {
        float qs = 0.f;
        #pragma unroll 8
        for (int b = 0; b < 64; ++b) qs += q[b * 32 + tid];
        dq = qs * colsum_s[tid];
        dq += __shfl_xor(dq, 1, 64);
        dq += __shfl_xor(dq, 2, 64);
        dq += __shfl_xor(dq, 4, 64);
        dq += __shfl_xor(dq, 8, 64);
        dq += __shfl_xor(dq, 16, 64);
    }
    if (tid == 0) {
        double q2sum = (double)r4[0] + (double)r4[1] + (double)r4[2] + (double)r4[3];
        double sumsq = (double)colsum_s[32];
        double Md    = (double)Mrows;
        double mean  = (Md * q2sum + 64.0 * sumsq - 2.0 * (double)dq) / (64.0 * Md);
        mean_out[0] = (float)mean;
    }
}

// ---------------------------------------------------------------------------
// Kernel 3: per-query final merge of block top-10s + episodic reward.
// ---------------------------------------------------------------------------
__global__ __launch_bounds__(256) void ep_final(
    const float* __restrict__ q, const float* __restrict__ part_top,
    const float* __restrict__ mean_in, float* __restrict__ out, int nb)
{
    const int b   = blockIdx.x;
    const int tid = threadIdx.x;
    __shared__ float l1[256][10];
    __shared__ float l2[32][10];
    __shared__ float q2s;

    if (tid < 64) {
        float x = (tid < 32) ? q[b * 32 + tid] : 0.f;
        float a = x * x;
        a += __shfl_xor(a, 1, 64);
        a += __shfl_xor(a, 2, 64);
        a += __shfl_xor(a, 4, 64);
        a += __shfl_xor(a, 8, 64);
        a += __shfl_xor(a, 16, 64);
        if (tid == 0) q2s = a;
    }

    float lst[10];
    #pragma unroll
    for (int i = 0; i < 10; ++i) lst[i] = -FLT_MAX;
    for (int i = tid; i < nb; i += 256) {
        const float* pp = part_top + ((size_t)i * 64 + b) * 10;
        #pragma unroll
        for (int r = 0; r < 10; ++r) top10_insert(lst, pp[r]);
    }
    #pragma unroll
    for (int r = 0; r < 10; ++r) l1[tid][r] = lst[r];
    __syncthreads();

    if (tid < 32) {
        float m[10];
        #pragma unroll
        for (int i = 0; i < 10; ++i) m[i] = -FLT_MAX;
        for (int j2 = 0; j2 < 8; ++j2) {
            #pragma unroll
            for (int r = 0; r < 10; ++r) top10_insert(m, l1[tid * 8 + j2][r]);
        }
        #pragma unroll
        for (int r = 0; r < 10; ++r) l2[tid][r] = m[r];
    }
    __syncthreads();

    if (tid == 0) {
        float m[10];
        #pragma unroll
        for (int i = 0; i < 10; ++i) m[i] = -FLT_MAX;
        for (int j2 = 0; j2 < 32; ++j2) {
            #pragma unroll
            for (int r = 0; r < 10; ++r) top10_insert(m, l2[j2][r]);
        }
        const float mean = mean_in[0];
        const float q2b  = q2s;
        float sum = 0.f;
        #pragma unroll
        for (int r = 0; r < 10; ++r) {
            float sq = m[r] + q2b;        // score + |q|^2 = squared distance
            sq = fmaxf(sq, 0.f);
            sum += KEPS / (sq / mean + KEPS);
        }
        out[b] = 1.0f / sqrtf(sum + DENOMC);
    }
}

// ---------------------------------------------------------------------------
extern "C" void kernel_launch(void* const* d_in, const int* in_sizes, int n_in,
                              void* d_out, int out_size, void* d_ws, size_t ws_size,
                              hipStream_t stream)
{
    const float* q   = (const float*)d_in[0];
    const float* mem = (const float*)d_in[1];
    float* out = (float*)d_out;

    const int Mrows  = in_sizes[1] / 32;   // 2,000,000
    const int ntiles = Mrows / 64;         // 31,250

    int nb = 2048;
    while (nb > 64 && ((size_t)nb * 673 + 1) * sizeof(float) > ws_size) nb >>= 1;
    if (nb > ntiles) nb = ntiles;

    float* part_top  = (float*)d_ws;                    // nb*64*10
    float* part_sums = part_top + (size_t)nb * 640;     // nb*33
    float* mean_slot = part_sums + (size_t)nb * 33;     // 1

    ep_main<<<dim3(nb), dim3(256), 0, stream>>>(q, mem, part_top, part_sums, nb, ntiles);
    ep_mean<<<dim3(1), dim3(256), 0, stream>>>(q, part_sums, mean_slot, nb, Mrows);
    ep_final<<<dim3(64), dim3(256), 0, stream>>>(q, part_top, mean_slot, out, nb);
}

// Round 2
// 95.958 us; speedup vs baseline: 1.2624x; 1.2624x over previous
//
#include <hip/hip_runtime.h>
#include <hip/hip_bf16.h>
#include <float.h>
#include <math.h>

typedef short short8 __attribute__((ext_vector_type(8)));
typedef float f32x4  __attribute__((ext_vector_type(4)));

#define KEPS   1e-5f
#define DENOMC 1e-5f

__device__ __forceinline__ short f2bf(float x) {
    return __builtin_bit_cast(short, __float2bfloat16(x));
}

// unsorted top-10, slot 0 always holds the min (admission gate)
__device__ __forceinline__ void top10_insert(float (&lst)[10], float s) {
    if (s > lst[0]) {
        lst[0] = s;
        #pragma unroll
        for (int i = 1; i < 10; ++i) {
            float lo = fminf(lst[0], lst[i]);
            float hi = fmaxf(lst[0], lst[i]);
            lst[0] = lo; lst[i] = hi;
        }
    }
}

// ---------------------------------------------------------------------------
// Kernel 1: stream memory once. Score S = m2_j - 2*q_b.m_j comes straight out
// of the MFMA: B-frag holds bf16(-2*q), C is initialized with the gathered
// row norms. Per-lane unconditional top-2 per (query, stream).
// ---------------------------------------------------------------------------
__global__ __launch_bounds__(256, 5) void ep_main(
    const float* __restrict__ q, const float* __restrict__ mem,
    float* __restrict__ part_top,    // [64][nb][10]
    float* __restrict__ part_sums,   // [33][nb]  (colsum rows 0..31, sumsq row 32)
    int nb, int ntiles)
{
    const int tid  = threadIdx.x;
    const int lane = tid & 63;
    const int wave = tid >> 6;
    const int g    = lane >> 4;   // k-chunk group (0..3), k = 8g..8g+7
    const int c    = lane & 15;   // A-row-within-subtile / query-col-within-16
    const int bid  = blockIdx.x;

    // B fragments (K x N = 32 x 16): lane holds -2*q[16n + c][8g .. 8g+8)
    short8 bfrag[4];
    #pragma unroll
    for (int n = 0; n < 4; ++n) {
        const float* qp = q + (n * 16 + c) * 32 + g * 8;
        float4 w0 = *(const float4*)qp;
        float4 w1 = *(const float4*)(qp + 4);
        short8 f;
        f[0]=f2bf(-2.f*w0.x); f[1]=f2bf(-2.f*w0.y); f[2]=f2bf(-2.f*w0.z); f[3]=f2bf(-2.f*w0.w);
        f[4]=f2bf(-2.f*w1.x); f[5]=f2bf(-2.f*w1.y); f[6]=f2bf(-2.f*w1.z); f[7]=f2bf(-2.f*w1.w);
        bfrag[n] = f;
    }

    float t1[4], t2[4];
    #pragma unroll
    for (int n = 0; n < 4; ++n) { t1[n] = -FLT_MAX; t2[n] = -FLT_MAX; }
    float cs[8];
    #pragma unroll
    for (int r = 0; r < 8; ++r) cs[r] = 0.f;
    float sumsq = 0.f;

    const size_t lane_off = (size_t)(wave * 16 + c) * 32 + (size_t)(g * 8);

    for (int tile = bid; tile < ntiles; tile += nb) {
        const float* p = mem + (size_t)tile * (64 * 32) + lane_off;
        float4 v0 = *(const float4*)p;
        float4 v1 = *(const float4*)(p + 4);

        float ps;
        ps = v0.x * v0.x;
        ps = fmaf(v0.y, v0.y, ps);
        ps = fmaf(v0.z, v0.z, ps);
        ps = fmaf(v0.w, v0.w, ps);
        ps = fmaf(v1.x, v1.x, ps);
        ps = fmaf(v1.y, v1.y, ps);
        ps = fmaf(v1.z, v1.z, ps);
        ps = fmaf(v1.w, v1.w, ps);
        sumsq += ps;
        cs[0] += v0.x; cs[1] += v0.y; cs[2] += v0.z; cs[3] += v0.w;
        cs[4] += v1.x; cs[5] += v1.y; cs[6] += v1.z; cs[7] += v1.w;

        // full row norm of row c (sum over the 4 k-chunk groups)
        float m2 = ps + __shfl_xor(ps, 16, 64);
        m2 = m2 + __shfl_xor(m2, 32, 64);
        // gather m2 for this lane's C-layout rows 4g+0..3
        f32x4 minit;
        minit[0] = __shfl(m2, 4 * g + 0, 64);
        minit[1] = __shfl(m2, 4 * g + 1, 64);
        minit[2] = __shfl(m2, 4 * g + 2, 64);
        minit[3] = __shfl(m2, 4 * g + 3, 64);

        // A fragment (M x K = 16 x 32): lane holds memrow(c)[8g .. 8g+8)
        short8 af;
        af[0]=f2bf(v0.x); af[1]=f2bf(v0.y); af[2]=f2bf(v0.z); af[3]=f2bf(v0.w);
        af[4]=f2bf(v1.x); af[5]=f2bf(v1.y); af[6]=f2bf(v1.z); af[7]=f2bf(v1.w);

        #pragma unroll
        for (int n = 0; n < 4; ++n) {
            f32x4 acc = __builtin_amdgcn_mfma_f32_16x16x32_bf16(af, bfrag[n], minit, 0, 0, 0);
            // acc[r] = m2(row 4g+r) - 2*dot(q_{16n+c}, m_{row 4g+r})
            #define T2UPD(S) { \
                float h1 = fmaxf(t1[n], (S)); float lo = fminf(t1[n], (S)); \
                float h2 = fmaxf(t2[n], lo); \
                t1[n] = h1; t2[n] = h2; }
            T2UPD(acc[0]) T2UPD(acc[1]) T2UPD(acc[2]) T2UPD(acc[3])
            #undef T2UPD
        }
    }

    // ---- block-level merge ----
    __shared__ float ltop[64][16][2];   // 8 KB
    __shared__ float red[4][4][8];
    __shared__ float ssred[4];

    const int slot = g + 4 * wave;      // 16 streams per query per block
    #pragma unroll
    for (int n = 0; n < 4; ++n) {
        const int b = n * 16 + c;
        ltop[b][slot][0] = t1[n];
        ltop[b][slot][1] = t2[n];
    }
    #pragma unroll
    for (int r = 0; r < 8; ++r) {
        float v = cs[r];
        v += __shfl_xor(v, 1, 64);
        v += __shfl_xor(v, 2, 64);
        v += __shfl_xor(v, 4, 64);
        v += __shfl_xor(v, 8, 64);
        cs[r] = v;
    }
    float ssv = sumsq;
    ssv += __shfl_xor(ssv, 1, 64);
    ssv += __shfl_xor(ssv, 2, 64);
    ssv += __shfl_xor(ssv, 4, 64);
    ssv += __shfl_xor(ssv, 8, 64);
    ssv += __shfl_xor(ssv, 16, 64);
    ssv += __shfl_xor(ssv, 32, 64);
    if (c == 0) {
        #pragma unroll
        for (int r = 0; r < 8; ++r) red[wave][g][r] = cs[r];
    }
    if (lane == 0) ssred[wave] = ssv;
    __syncthreads();

    if (tid < 32) {
        float a = red[0][tid >> 3][tid & 7] + red[1][tid >> 3][tid & 7]
                + red[2][tid >> 3][tid & 7] + red[3][tid >> 3][tid & 7];
        part_sums[(size_t)tid * nb + bid] = a;
    } else if (tid == 32) {
        part_sums[(size_t)32 * nb + bid] = ssred[0] + ssred[1] + ssred[2] + ssred[3];
    }

    if (tid < 64) {
        float lst[10];
        #pragma unroll
        for (int i = 0; i < 10; ++i) lst[i] = -FLT_MAX;
        for (int s2 = 0; s2 < 16; ++s2) {
            top10_insert(lst, ltop[tid][s2][0]);
            top10_insert(lst, ltop[tid][s2][1]);
        }
        #pragma unroll
        for (int i = 0; i < 10; ++i)
            part_top[((size_t)tid * nb + bid) * 10 + i] = lst[i];
    }
}

// ---------------------------------------------------------------------------
// Kernel 2 (fused tail): 64 blocks, one per query. Each block redundantly
// reduces part_sums -> closed-form global mean (coalesced [33][nb] layout,
// L2-hot), merges its query's nb block-top-10s, and emits the reward.
// ---------------------------------------------------------------------------
__global__ __launch_bounds__(256) void ep_tail(
    const float* __restrict__ q, const float* __restrict__ part_top,
    const float* __restrict__ part_sums, float* __restrict__ out,
    int nb, int Mrows)
{
    const int b    = blockIdx.x;
    const int tid  = threadIdx.x;
    const int lane = tid & 63;
    const int wave = tid >> 6;

    __shared__ float smem[256 * 33];    // 33.8 KB, reused across phases
    __shared__ float colsum_a[33];
    __shared__ float w4[4];
    __shared__ float mean_s, q2_s;

    // q2 of this block's query
    if (tid < 64) {
        float x = (tid < 32) ? q[b * 32 + tid] : 0.f;
        float a = x * x;
        a += __shfl_xor(a, 1, 64);
        a += __shfl_xor(a, 2, 64);
        a += __shfl_xor(a, 4, 64);
        a += __shfl_xor(a, 8, 64);
        a += __shfl_xor(a, 16, 64);
        if (tid == 0) q2_s = a;
    }

    // sum of squares of all query elements (2048 elems, 8 per thread)
    float a2 = 0.f;
    #pragma unroll
    for (int e = 0; e < 8; ++e) {
        float x = q[tid * 8 + e];
        a2 = fmaf(x, x, a2);
    }
    a2 += __shfl_xor(a2, 1, 64);
    a2 += __shfl_xor(a2, 2, 64);
    a2 += __shfl_xor(a2, 4, 64);
    a2 += __shfl_xor(a2, 8, 64);
    a2 += __shfl_xor(a2, 16, 64);
    a2 += __shfl_xor(a2, 32, 64);
    if (lane == 0) w4[wave] = a2;

    // phase A: reduce the 33 partial-sum rows (coalesced over i)
    float acc[33];
    #pragma unroll
    for (int c2 = 0; c2 < 33; ++c2) acc[c2] = 0.f;
    for (int i = tid; i < nb; i += 256) {
        #pragma unroll
        for (int c2 = 0; c2 < 33; ++c2) acc[c2] += part_sums[(size_t)c2 * nb + i];
    }
    #pragma unroll
    for (int c2 = 0; c2 < 33; ++c2) smem[tid * 33 + c2] = acc[c2];
    __syncthreads();
    if (tid < 33) {
        float a = 0.f;
        #pragma unroll 16
        for (int j = 0; j < 256; ++j) a += smem[j * 33 + tid];
        colsum_a[tid] = a;
    }
    __syncthreads();

    if (tid < 32) {
        float qs = 0.f;
        #pragma unroll 8
        for (int bb = 0; bb < 64; ++bb) qs += q[bb * 32 + tid];
        float dq = qs * colsum_a[tid];
        dq += __shfl_xor(dq, 1, 64);
        dq += __shfl_xor(dq, 2, 64);
        dq += __shfl_xor(dq, 4, 64);
        dq += __shfl_xor(dq, 8, 64);
        dq += __shfl_xor(dq, 16, 64);
        if (tid == 0) {
            double q2sum = (double)w4[0] + (double)w4[1] + (double)w4[2] + (double)w4[3];
            double sumsq = (double)colsum_a[32];
            double Md    = (double)Mrows;
            mean_s = (float)((Md * q2sum + 64.0 * sumsq - 2.0 * (double)dq) / (64.0 * Md));
        }
    }
    __syncthreads();

    // phase B: merge this query's nb candidate lists (contiguous, L2-hot)
    float lst[10];
    #pragma unroll
    for (int i = 0; i < 10; ++i) lst[i] = -FLT_MAX;
    const float* pt = part_top + (size_t)b * nb * 10;
    for (int i = tid; i < nb; i += 256) {
        const float* pp = pt + (size_t)i * 10;
        #pragma unroll
        for (int r = 0; r < 10; ++r) top10_insert(lst, pp[r]);
    }
    #pragma unroll
    for (int r = 0; r < 10; ++r) smem[tid * 10 + r] = lst[r];
    __syncthreads();

    if (tid < 32) {
        float m[10];
        #pragma unroll
        for (int i = 0; i < 10; ++i) m[i] = -FLT_MAX;
        for (int j2 = 0; j2 < 8; ++j2) {
            #pragma unroll
            for (int r = 0; r < 10; ++r) top10_insert(m, smem[(tid * 8 + j2) * 10 + r]);
        }
        #pragma unroll
        for (int r = 0; r < 10; ++r) smem[2560 + tid * 10 + r] = m[r];
    }
    __syncthreads();

    if (tid == 0) {
        float m[10];
        #pragma unroll
        for (int i = 0; i < 10; ++i) m[i] = -FLT_MAX;
        for (int j2 = 0; j2 < 32; ++j2) {
            #pragma unroll
            for (int r = 0; r < 10; ++r) top10_insert(m, smem[2560 + j2 * 10 + r]);
        }
        const float mean = mean_s;
        const float q2b  = q2_s;
        float sum = 0.f;
        #pragma unroll
        for (int r = 0; r < 10; ++r) {
            float sq = m[r] + q2b;        // score + |q|^2 = squared distance
            sq = fmaxf(sq, 0.f);
            sum += KEPS / (sq / mean + KEPS);
        }
        out[b] = 1.0f / sqrtf(sum + DENOMC);
    }
}

// ---------------------------------------------------------------------------
extern "C" void kernel_launch(void* const* d_in, const int* in_sizes, int n_in,
                              void* d_out, int out_size, void* d_ws, size_t ws_size,
                              hipStream_t stream)
{
    const float* q   = (const float*)d_in[0];
    const float* mem = (const float*)d_in[1];
    float* out = (float*)d_out;

    const int Mrows  = in_sizes[1] / 32;   // 2,000,000
    const int ntiles = Mrows / 64;         // 31,250

    // 256 CUs x 5 resident blocks -> one clean residency round
    int nb = 1280;
    while (nb > 64 && ((size_t)nb * 673 + 64) * sizeof(float) > ws_size) nb >>= 1;
    if (nb > ntiles) nb = ntiles;

    float* part_top  = (float*)d_ws;                         // [64][nb][10]
    float* part_sums = part_top + (size_t)64 * nb * 10;      // [33][nb]

    ep_main<<<dim3(nb), dim3(256), 0, stream>>>(q, mem, part_top, part_sums, nb, ntiles);
    ep_tail<<<dim3(64), dim3(256), 0, stream>>>(q, part_top, part_sums, out, nb, Mrows);
}